// Round 8
// baseline (4876.263 us; speedup 1.0000x reference)
//
#include <hip/hip_runtime.h>
#include <math.h>

typedef __bf16 bf16_t;
typedef __bf16 bf16x4 __attribute__((ext_vector_type(4)));
typedef __bf16 bf16x8 __attribute__((ext_vector_type(8)));
typedef float f32x4 __attribute__((ext_vector_type(4)));
typedef unsigned long long u64;

#define MFMA_16x16x32(A, B, C) __builtin_amdgcn_mfma_f32_16x16x32_bf16((A), (B), (C), 0, 0, 0)

static constexpr int Bn = 64;    // batch
static constexpr int Tn = 512;   // time
static constexpr int Dn = 1024;  // input dim
static constexpr int Hn = 2048;  // hidden
static constexpr int Cn = 5;     // classes
static constexpr int NGB = 128;  // blocks per batch-group
static constexpr int NGRP = 2;   // batch groups (32 rows each)
static constexpr int NBT = NGB * NGRP;  // 256 blocks = full GPU
static constexpr int NW = 16;    // waves per block (1024 threads)

// LDS swizzle for the xw GEMM tiles (32 bf16 = 64B rows)
#define SWZ64(row, kb)  ((((row) * 64) + (kb)) ^ (((row) & 3) << 4))

// ---------------- conversion kernels ----------------
__global__ __launch_bounds__(256) void cvt_bf16_k(const float* __restrict__ in,
                                                  bf16_t* __restrict__ out, int n4) {
  int i = blockIdx.x * 256 + threadIdx.x;
  if (i >= n4) return;
  float4 v = reinterpret_cast<const float4*>(in)[i];
  bf16x4 o;
  o[0] = (bf16_t)v.x; o[1] = (bf16_t)v.y; o[2] = (bf16_t)v.z; o[3] = (bf16_t)v.w;
  reinterpret_cast<bf16x4*>(out)[i] = o;
}

__global__ __launch_bounds__(256) void cvt_hilo_k(const float* __restrict__ in,
                                                  bf16_t* __restrict__ hi,
                                                  bf16_t* __restrict__ lo, int n4) {
  int i = blockIdx.x * 256 + threadIdx.x;
  if (i >= n4) return;
  float4 v = reinterpret_cast<const float4*>(in)[i];
  float f[4] = {v.x, v.y, v.z, v.w};
  bf16x4 h, l;
#pragma unroll
  for (int j = 0; j < 4; ++j) {
    bf16_t hb = (bf16_t)f[j];
    h[j] = hb;
    l[j] = (bf16_t)(f[j] - (float)hb);
  }
  reinterpret_cast<bf16x4*>(hi)[i] = h;
  reinterpret_cast<bf16x4*>(lo)[i] = l;
}

// ---------------- xw projection GEMM ----------------
__global__ __launch_bounds__(256) void gemm_xw_k(const float* __restrict__ A,
                                                 const bf16_t* __restrict__ Bw,
                                                 const float* __restrict__ bias,
                                                 bf16_t* __restrict__ C) {
  constexpr int K = Dn;
  constexpr int N = Hn;
  constexpr int NT = K / 32;
  __shared__ char As[2][128 * 64];
  __shared__ char Bs[2][128 * 64];

  const int tid = threadIdx.x;
  const int lane = tid & 63;
  const int wv = tid >> 6;
  const int wm = (wv >> 1) * 64;
  const int wn = (wv & 1) * 64;
  const int cl = lane & 15;
  const int kh = lane >> 4;
  const long m0 = (long)blockIdx.y * 128;
  const long n0 = (long)blockIdx.x * 128;

  const int srow = tid >> 1;
  const int scolb = (tid & 1) * 32;

  f32x4 acc[4][4] = {};
  float4 pa[4];
  uint4 pb[2];

  auto issue = [&](int kt) {
    const float* ap = A + (m0 + srow) * K + kt * 32 + (tid & 1) * 16;
#pragma unroll
    for (int i = 0; i < 4; ++i) pa[i] = reinterpret_cast<const float4*>(ap)[i];
    const bf16_t* bp = Bw + (n0 + srow) * K + kt * 32 + (tid & 1) * 16;
    pb[0] = reinterpret_cast<const uint4*>(bp)[0];
    pb[1] = reinterpret_cast<const uint4*>(bp)[1];
  };
  auto commit = [&](int buf) {
    bf16x8 a0, a1;
    a0[0] = (bf16_t)pa[0].x; a0[1] = (bf16_t)pa[0].y; a0[2] = (bf16_t)pa[0].z; a0[3] = (bf16_t)pa[0].w;
    a0[4] = (bf16_t)pa[1].x; a0[5] = (bf16_t)pa[1].y; a0[6] = (bf16_t)pa[1].z; a0[7] = (bf16_t)pa[1].w;
    a1[0] = (bf16_t)pa[2].x; a1[1] = (bf16_t)pa[2].y; a1[2] = (bf16_t)pa[2].z; a1[3] = (bf16_t)pa[2].w;
    a1[4] = (bf16_t)pa[3].x; a1[5] = (bf16_t)pa[3].y; a1[6] = (bf16_t)pa[3].z; a1[7] = (bf16_t)pa[3].w;
    *reinterpret_cast<bf16x8*>(&As[buf][SWZ64(srow, scolb)]) = a0;
    *reinterpret_cast<bf16x8*>(&As[buf][SWZ64(srow, scolb + 16)]) = a1;
    *reinterpret_cast<uint4*>(&Bs[buf][SWZ64(srow, scolb)]) = pb[0];
    *reinterpret_cast<uint4*>(&Bs[buf][SWZ64(srow, scolb + 16)]) = pb[1];
  };

  issue(0);
  commit(0);
  for (int kt = 0; kt < NT; ++kt) {
    const int buf = kt & 1;
    __syncthreads();
    if (kt + 1 < NT) issue(kt + 1);
    bf16x8 af[4], bfr[4];
#pragma unroll
    for (int i = 0; i < 4; ++i)
      af[i] = *reinterpret_cast<const bf16x8*>(&As[buf][SWZ64(wm + i * 16 + cl, kh * 16)]);
#pragma unroll
    for (int j = 0; j < 4; ++j)
      bfr[j] = *reinterpret_cast<const bf16x8*>(&Bs[buf][SWZ64(wn + j * 16 + cl, kh * 16)]);
#pragma unroll
    for (int i = 0; i < 4; ++i)
#pragma unroll
      for (int j = 0; j < 4; ++j)
        acc[i][j] = MFMA_16x16x32(af[i], bfr[j], acc[i][j]);
    if (kt + 1 < NT) commit((kt + 1) & 1);
  }

  const int rl4 = kh * 4;
#pragma unroll
  for (int j = 0; j < 4; ++j) {
    const long gcol = n0 + wn + j * 16 + cl;
    const float bv = bias[gcol];
#pragma unroll
    for (int i = 0; i < 4; ++i) {
      const long grow = m0 + wm + i * 16 + rl4;
#pragma unroll
      for (int q = 0; q < 4; ++q)
        C[(grow + q) * N + gcol] = (bf16_t)(acc[i][j][q] + bv);
    }
  }
}

// ---------------- persistent scan kernel ----------------
// Round-8: 256 blocks x 1024 threads (16 waves), r6 geometry
// (2 groups x 128 blocks, 16 cols/block, waves = 2 row-tiles x 8 k-splits).
// Changes vs r6/r7:
//   1. U FRAGMENTS IN VGPRS: the wave's 16 B-operand fragments (64 VGPRs) are
//      hoisted from LDS once before the t-loop (U is loop-invariant). Zero
//      steady-state LDS reads -> kills the 1.5e8 bank-conflict cycles.
//   2. ONE __syncthreads PER STEP: red scratch is double-buffered in the LDS
//      space freed by (1); storer waves ack their own h stores wave-locally
//      (r7-proven) so no block-wide vmcnt drain.
//   3. TARGETED DENSE-FLAG SELF-GATING: flags are dense u32[block][rowtile];
//      wave (r,ks) polls only its 16 producer flags, which span 128B = 2 hot
//      MALL lines (r7's flood was 16 scattered lines/wave). All waves
//      self-gate; no post-poll sync.
//   4. XCD-ALIGNED GROUPS: group = ((bid&7)>=4) -> with %8 round-robin XCD
//      dispatch each XCD fills only its own group's h slice (halves h fetch).
//      Pure perf heuristic; correctness placement-independent.
// Coherence (r3, kept): h stores sc0sc1 -> MALL, acked (wave-local) before
// flag; h loads plain cached on virgin rotated slots (no fence). Fallback
// rot=0: ping-pong + per-wave acquire fence after each gate.
__global__ __launch_bounds__(1024, 1) void scan_k(
    const bf16_t* __restrict__ Uhi, const bf16_t* __restrict__ Ulo,
    const float* __restrict__ Ub, const bf16_t* __restrict__ XW,
    bf16_t* __restrict__ Hc, long Hstep, int rot,
    const bf16_t* __restrict__ V1w, const float* __restrict__ V1b,
    float* __restrict__ Z1,
    const float* __restrict__ V2w, const float* __restrict__ V2b,
    float* __restrict__ out, unsigned* __restrict__ slots) {
  extern __shared__ char smem[];
  char* Uh_s = smem;                        // 64 KB staging (dead after hoist)
  char* Ul_s = smem + 65536;                // 64 KB staging (dead after hoist)
  float* red0 = (float*)smem;               // overlay: red[2][16][256] = 32 KB

  const int tid = threadIdx.x;
  const int lane = tid & 63;
  const int wv = tid >> 6;             // 0..15
  const int cl = lane & 15;
  const int kh = lane >> 4;
  const int bid = blockIdx.x;
  // XCD-aligned group split (assumes bid%8 = XCD round-robin; perf-only)
  const int g = ((bid & 7) >= 4) ? 1 : 0;
  const int j = (bid >> 3) * 4 + (bid & 3);  // group-local block id 0..127
  const int n0 = j * 16;               // owned columns
  const int r = wv >> 3;               // row-tile (0/1) within group slice
  const int ks = wv & 7;               // k-split (0..7), 256 cols each
  const int row0 = 32 * g + 16 * r;    // global batch row base for this wave

  // dense flags: u32 per (block, row-tile). group base = g*256 u32.
  unsigned* gflags = slots + (size_t)g * (NGB * 2);
  const int fself = j * 2 + r;
  const int fprod = (ks * 16 + (lane & 15)) * 2 + r;  // 16 flags in 128B

  // ---- stage U slice into LDS (once; 1024 threads: 64 segs x 16 cols) ----
  {
    const int col = tid >> 6;          // 0..15
    const int seg = tid & 63;          // 0..63
    const char* srch = reinterpret_cast<const char*>(Uhi + (long)(n0 + col) * Hn);
    const char* srcl = reinterpret_cast<const char*>(Ulo + (long)(n0 + col) * Hn);
#pragma unroll
    for (int c = 0; c < 4; ++c) {
      const int byteoff = seg * 16 + c * 1024;
      uint4 vh = *reinterpret_cast<const uint4*>(srch + byteoff);
      uint4 vl = *reinterpret_cast<const uint4*>(srcl + byteoff);
      const int sw = col * 4096 + (byteoff ^ ((col & 7) << 4));
      *reinterpret_cast<uint4*>(Uh_s + sw) = vh;
      *reinterpret_cast<uint4*>(Ul_s + sw) = vl;
    }
  }
  __syncthreads();

  // ---- hoist this wave's 16 U fragments into VGPRs (loop-invariant) ----
  const int lds_base = cl * 4096;
  const int lds_x = (cl & 7) << 4;
  const int kbase = ks * 512;          // byte offset of this wave's k-split
  bf16x8 Ubh0[4], Ubl0[4], Ubh1[4], Ubl1[4];  // 64 VGPRs total
#pragma unroll
  for (int it = 0; it < 4; ++it) {
    const int kb0 = kbase + it * 128 + kh * 16;
    const int kb1 = kb0 + 64;
    Ubh0[it] = *reinterpret_cast<const bf16x8*>(Uh_s + lds_base + (kb0 ^ lds_x));
    Ubl0[it] = *reinterpret_cast<const bf16x8*>(Ul_s + lds_base + (kb0 ^ lds_x));
    Ubh1[it] = *reinterpret_cast<const bf16x8*>(Uh_s + lds_base + (kb1 ^ lds_x));
    Ubl1[it] = *reinterpret_cast<const bf16x8*>(Ul_s + lds_base + (kb1 ^ lds_x));
  }
  __syncthreads();  // all waves hoisted; LDS reusable as red[2]

  // store-side mapping (storer waves ks==0): one coalesced u64 per lane
  const int st_row = lane >> 2;        // 0..15
  const int st_cg = lane & 3;          // col group *4
  const bool storer = (ks == 0);

  float4 bv4 = {0.f, 0.f, 0.f, 0.f};
  if (storer) bv4 = *reinterpret_cast<const float4*>(Ub + n0 + st_cg * 4);
  const long xw_off = (long)(row0 + st_row) * (Tn * Hn) + n0 + st_cg * 4;

  // prefetch xw add-path for t=0 (storer waves)
  bf16x4 ad = {};
  if (storer) ad = *reinterpret_cast<const bf16x4*>(XW + xw_off);

  // h slot pointers: t reads hin, writes hout.
  bf16_t* hin = Hc;            // slot 0 = zeros
  bf16_t* hout = Hc + Hstep;   // slot 1

  for (int t = 0; t < Tn; ++t) {
    // ---- targeted self-gate: my 16 producers published h_t ----
    {
      const unsigned tgt = (unsigned)t;  // t=0: flags memset 0 -> passes
      for (;;) {
        unsigned v = __hip_atomic_load(gflags + fprod, __ATOMIC_RELAXED,
                                       __HIP_MEMORY_SCOPE_AGENT);
        if (__all((int)(v >= tgt))) break;
      }
      asm volatile("" ::: "memory");  // don't hoist h loads above the gate
      if (!rot) __builtin_amdgcn_fence(__ATOMIC_ACQUIRE, "agent");
    }

    const bf16_t* arow = hin + (long)(row0 + cl) * Hn + ks * 256 + kh * 8;

    f32x4 ah0 = {}, ah1 = {}, al0 = {}, al1 = {};
#pragma unroll
    for (int it = 0; it < 4; ++it) {
      bf16x8 a0 = *reinterpret_cast<const bf16x8*>(arow + it * 64);
      bf16x8 a1 = *reinterpret_cast<const bf16x8*>(arow + it * 64 + 32);
      ah0 = MFMA_16x16x32(a0, Ubh0[it], ah0);
      al0 = MFMA_16x16x32(a0, Ubl0[it], al0);
      ah1 = MFMA_16x16x32(a1, Ubh1[it], ah1);
      al1 = MFMA_16x16x32(a1, Ubl1[it], al1);
    }

    // k-split partials -> double-buffered red
    float* red = red0 + (t & 1) * 4096;
#pragma unroll
    for (int q = 0; q < 4; ++q)
      red[wv * 256 + (kh * 4 + q) * 16 + cl] = ah0[q] + ah1[q] + al0[q] + al1[q];

    __syncthreads();  // the ONLY block sync per step

    // storer waves: combine 8 k-splits (float4, conflict-free), bias+xw+relu,
    // coalesced sc0sc1 store, WAVE-LOCAL ack, dense flag.
    if (storer) {
      const int ri = st_row * 16 + st_cg * 4;
      float4 s = {0.f, 0.f, 0.f, 0.f};
#pragma unroll
      for (int w = 0; w < 8; ++w) {
        float4 p = *reinterpret_cast<const float4*>(&red[(wv + w) * 256 + ri]);
        s.x += p.x; s.y += p.y; s.z += p.z; s.w += p.w;
      }
      bf16x4 hv;
      hv[0] = (bf16_t)fmaxf(s.x + bv4.x + (float)ad[0], 0.f);
      hv[1] = (bf16_t)fmaxf(s.y + bv4.y + (float)ad[1], 0.f);
      hv[2] = (bf16_t)fmaxf(s.z + bv4.z + (float)ad[2], 0.f);
      hv[3] = (bf16_t)fmaxf(s.w + bv4.w + (float)ad[3], 0.f);
      __hip_atomic_store(
          reinterpret_cast<u64*>(hout + (long)(row0 + st_row) * Hn + n0 + st_cg * 4),
          *reinterpret_cast<const u64*>(&hv), __ATOMIC_RELAXED,
          __HIP_MEMORY_SCOPE_AGENT);
      asm volatile("s_waitcnt vmcnt(0)" ::: "memory");  // h acked at MALL
      if (lane == 0)
        __hip_atomic_store(gflags + fself, (unsigned)(t + 1), __ATOMIC_RELAXED,
                           __HIP_MEMORY_SCOPE_AGENT);
      // prefetch xw for t+1 (in flight under next gate)
      if (t + 1 < Tn)
        ad = *reinterpret_cast<const bf16x4*>(XW + xw_off + (long)(t + 1) * Hn);
    }

    // advance slots
    bf16_t* nn = hout;
    hout = rot ? (hout + Hstep) : hin;
    hin = nn;
  }

  // ---- V1 layer: z1 = relu(h_last @ V1^T + b1) for this group's 32 rows ----
  {
    const unsigned tgt = (unsigned)Tn;
    for (;;) {
      unsigned v = __hip_atomic_load(gflags + fprod, __ATOMIC_RELAXED,
                                     __HIP_MEMORY_SCOPE_AGENT);
      if (__all((int)(v >= tgt))) break;
    }
    asm volatile("" ::: "memory");
    if (!rot) __builtin_amdgcn_fence(__ATOMIC_ACQUIRE, "agent");

    const bf16_t* arow = hin + (long)(row0 + cl) * Hn + ks * 256 + kh * 8;
    const bf16_t* vrow = V1w + (long)(n0 + cl) * Hn + ks * 256 + kh * 8;
    f32x4 z0 = {}, z1a = {};
#pragma unroll
    for (int it = 0; it < 4; ++it) {
      bf16x8 a0 = *reinterpret_cast<const bf16x8*>(arow + it * 64);
      bf16x8 a1 = *reinterpret_cast<const bf16x8*>(arow + it * 64 + 32);
      bf16x8 b0 = *reinterpret_cast<const bf16x8*>(vrow + it * 64);
      bf16x8 b1 = *reinterpret_cast<const bf16x8*>(vrow + it * 64 + 32);
      z0 = MFMA_16x16x32(a0, b0, z0);
      z1a = MFMA_16x16x32(a1, b1, z1a);
    }
    // buf0 is safe: its last reader (storer of t=510) finished before the
    // t=511 __syncthreads, which every wave has passed.
    float* red = red0;
#pragma unroll
    for (int q = 0; q < 4; ++q)
      red[wv * 256 + (kh * 4 + q) * 16 + cl] = z0[q] + z1a[q];
    __syncthreads();
    if (storer) {
      const int ri = st_row * 16 + st_cg * 4;
      float4 s = {0.f, 0.f, 0.f, 0.f};
#pragma unroll
      for (int w = 0; w < 8; ++w) {
        float4 p = *reinterpret_cast<const float4*>(&red[(wv + w) * 256 + ri]);
        s.x += p.x; s.y += p.y; s.z += p.z; s.w += p.w;
      }
      float4 vb = *reinterpret_cast<const float4*>(V1b + n0 + st_cg * 4);
      float4 o;
      o.x = fmaxf(s.x + vb.x, 0.f);
      o.y = fmaxf(s.y + vb.y, 0.f);
      o.z = fmaxf(s.z + vb.z, 0.f);
      o.w = fmaxf(s.w + vb.w, 0.f);
      *reinterpret_cast<float4*>(Z1 + (long)(row0 + st_row) * Hn + n0 + st_cg * 4) = o;
    }
  }

  // ---- FULL-grid barrier before head reads Z1 (release + acquire, once) ----
  {
    unsigned* fbar = slots + (size_t)NGRP * NGB * 2;  // after dense flags
    __syncthreads();
    if (tid == 0)
      __hip_atomic_store(fbar + (size_t)bid * 32, 1u,
                         __ATOMIC_RELEASE, __HIP_MEMORY_SCOPE_AGENT);
    if (tid < 64) {
      for (;;) {
        unsigned a = __hip_atomic_load(fbar + (size_t)tid * 32,
                                       __ATOMIC_RELAXED, __HIP_MEMORY_SCOPE_AGENT);
        unsigned b = __hip_atomic_load(fbar + (size_t)(tid + 64) * 32,
                                       __ATOMIC_RELAXED, __HIP_MEMORY_SCOPE_AGENT);
        unsigned c = __hip_atomic_load(fbar + (size_t)(tid + 128) * 32,
                                       __ATOMIC_RELAXED, __HIP_MEMORY_SCOPE_AGENT);
        unsigned d = __hip_atomic_load(fbar + (size_t)(tid + 192) * 32,
                                       __ATOMIC_RELAXED, __HIP_MEMORY_SCOPE_AGENT);
        if (__all((int)((a >= 1u) && (b >= 1u) && (c >= 1u) && (d >= 1u)))) break;
      }
      __builtin_amdgcn_fence(__ATOMIC_ACQUIRE, "agent");
    }
    __syncthreads();
  }

  // ---- head: z2 = relu(z1 @ V2^T + b2); out = log_softmax ----
  if (bid < Bn) {
    const int b = bid;
    float p[Cn] = {0.f, 0.f, 0.f, 0.f, 0.f};
    for (int jj = tid; jj < Hn; jj += 1024) {
      const float x = Z1[(long)b * Hn + jj];
#pragma unroll
      for (int c = 0; c < Cn; ++c) p[c] += x * V2w[(long)c * Hn + jj];
    }
#pragma unroll
    for (int c = 0; c < Cn; ++c)
      for (int off = 32; off; off >>= 1) p[c] += __shfl_down(p[c], off, 64);

    float* redh = reinterpret_cast<float*>(smem);
    if (lane == 0) {
#pragma unroll
      for (int c = 0; c < Cn; ++c) redh[c * NW + wv] = p[c];
    }
    __syncthreads();
    if (tid == 0) {
      float z[Cn];
      float mx = 0.f;
#pragma unroll
      for (int c = 0; c < Cn; ++c) {
        float s16 = 0.f;
#pragma unroll
        for (int w = 0; w < NW; ++w) s16 += redh[c * NW + w];
        z[c] = fmaxf(s16 + V2b[c], 0.f);
        mx = fmaxf(mx, z[c]);
      }
      float s = 0.f;
#pragma unroll
      for (int c = 0; c < Cn; ++c) s += expf(z[c] - mx);
      const float ls = logf(s);
#pragma unroll
      for (int c = 0; c < Cn; ++c) out[b * Cn + c] = z[c] - mx - ls;
    }
  }
}

// ---------------- host ----------------
extern "C" void kernel_launch(void* const* d_in, const int* in_sizes, int n_in,
                              void* d_out, int out_size, void* d_ws, size_t ws_size,
                              hipStream_t stream) {
  const float* inputs = (const float*)d_in[0];
  const float* W_w = (const float*)d_in[1];
  const float* W_b = (const float*)d_in[2];
  const float* U_w = (const float*)d_in[3];
  const float* U_b = (const float*)d_in[4];
  const float* V1_w = (const float*)d_in[5];
  const float* V1_b = (const float*)d_in[6];
  const float* V2_w = (const float*)d_in[7];
  const float* V2_b = (const float*)d_in[8];
  float* out = (float*)d_out;

  size_t off = 0;
  auto alloc = [&](size_t bytes) {
    void* p = (char*)d_ws + off;
    off += (bytes + 255) & ~(size_t)255;
    return p;
  };
  bf16_t* Wbf = (bf16_t*)alloc((size_t)Hn * Dn * 2);
  bf16_t* Uhi = (bf16_t*)alloc((size_t)Hn * Hn * 2);
  bf16_t* Ulo = (bf16_t*)alloc((size_t)Hn * Hn * 2);
  bf16_t* V1bf = (bf16_t*)alloc((size_t)Hn * Hn * 2);
  bf16_t* XW = (bf16_t*)alloc((size_t)Bn * Tn * Hn * 2);
  float* Z1 = (float*)alloc((size_t)Bn * Hn * 4);
  // dense flags (NGRP*NGB*2 u32 = 2 KB) + full-barrier slots (NBT*32 u32)
  const size_t slots_bytes = (size_t)(NGRP * NGB * 2 + NBT * 32) * 4;
  unsigned* slots = (unsigned*)alloc(slots_bytes);

  // h chain: rotation if the workspace fits Tn+1 virgin slots, else ping-pong.
  const size_t slot_bytes = (size_t)Bn * Hn * 2;  // 256 KB
  const size_t rot_bytes = (size_t)(Tn + 1) * slot_bytes;
  const int rot = (ws_size - off) >= (rot_bytes + 256) ? 1 : 0;
  bf16_t* Hc = (bf16_t*)alloc(rot ? rot_bytes : 2 * slot_bytes);
  (void)ws_size;

  (void)hipFuncSetAttribute((const void*)scan_k,
                            hipFuncAttributeMaxDynamicSharedMemorySize, 131072);

  cvt_bf16_k<<<(Hn * Dn / 4 + 255) / 256, 256, 0, stream>>>(W_w, Wbf, Hn * Dn / 4);
  cvt_hilo_k<<<(Hn * Hn / 4 + 255) / 256, 256, 0, stream>>>(U_w, Uhi, Ulo, Hn * Hn / 4);
  cvt_bf16_k<<<(Hn * Hn / 4 + 255) / 256, 256, 0, stream>>>(V1_w, V1bf, Hn * Hn / 4);

  gemm_xw_k<<<dim3(Hn / 128, (Bn * Tn) / 128), 256, 0, stream>>>(inputs, Wbf, W_b, XW);

  (void)hipMemsetAsync(Hc, 0, slot_bytes, stream);  // slot 0 = h_0 = zeros
  (void)hipMemsetAsync(slots, 0, slots_bytes, stream);

  scan_k<<<NBT, 1024, 131072, stream>>>(Uhi, Ulo, U_b, XW, Hc, (long)Bn * Hn, rot,
                                        V1bf, V1_b, Z1, V2_w, V2_b, out, slots);
}

// Round 9
// 3247.061 us; speedup vs baseline: 1.5017x; 1.5017x over previous
//
#include <hip/hip_runtime.h>
#include <math.h>

typedef __bf16 bf16_t;
typedef __bf16 bf16x4 __attribute__((ext_vector_type(4)));
typedef __bf16 bf16x8 __attribute__((ext_vector_type(8)));
typedef float f32x4 __attribute__((ext_vector_type(4)));
typedef unsigned long long u64;

#define MFMA_16x16x32(A, B, C) __builtin_amdgcn_mfma_f32_16x16x32_bf16((A), (B), (C), 0, 0, 0)

static constexpr int Bn = 64;    // batch
static constexpr int Tn = 512;   // time
static constexpr int Dn = 1024;  // input dim
static constexpr int Hn = 2048;  // hidden
static constexpr int Cn = 5;     // classes
static constexpr int NGB = 128;  // blocks per batch-group
static constexpr int NGRP = 2;   // batch groups (32 rows each)
static constexpr int NBT = NGB * NGRP;  // 256 blocks = full GPU
static constexpr int NW = 16;    // waves per block (1024 threads)

// LDS swizzle for the xw GEMM tiles (32 bf16 = 64B rows)
#define SWZ64(row, kb)  ((((row) * 64) + (kb)) ^ (((row) & 3) << 4))

// ---------------- conversion kernels ----------------
__global__ __launch_bounds__(256) void cvt_bf16_k(const float* __restrict__ in,
                                                  bf16_t* __restrict__ out, int n4) {
  int i = blockIdx.x * 256 + threadIdx.x;
  if (i >= n4) return;
  float4 v = reinterpret_cast<const float4*>(in)[i];
  bf16x4 o;
  o[0] = (bf16_t)v.x; o[1] = (bf16_t)v.y; o[2] = (bf16_t)v.z; o[3] = (bf16_t)v.w;
  reinterpret_cast<bf16x4*>(out)[i] = o;
}

__global__ __launch_bounds__(256) void cvt_hilo_k(const float* __restrict__ in,
                                                  bf16_t* __restrict__ hi,
                                                  bf16_t* __restrict__ lo, int n4) {
  int i = blockIdx.x * 256 + threadIdx.x;
  if (i >= n4) return;
  float4 v = reinterpret_cast<const float4*>(in)[i];
  float f[4] = {v.x, v.y, v.z, v.w};
  bf16x4 h, l;
#pragma unroll
  for (int j = 0; j < 4; ++j) {
    bf16_t hb = (bf16_t)f[j];
    h[j] = hb;
    l[j] = (bf16_t)(f[j] - (float)hb);
  }
  reinterpret_cast<bf16x4*>(hi)[i] = h;
  reinterpret_cast<bf16x4*>(lo)[i] = l;
}

// ---------------- xw projection GEMM ----------------
__global__ __launch_bounds__(256) void gemm_xw_k(const float* __restrict__ A,
                                                 const bf16_t* __restrict__ Bw,
                                                 const float* __restrict__ bias,
                                                 bf16_t* __restrict__ C) {
  constexpr int K = Dn;
  constexpr int N = Hn;
  constexpr int NT = K / 32;
  __shared__ char As[2][128 * 64];
  __shared__ char Bs[2][128 * 64];

  const int tid = threadIdx.x;
  const int lane = tid & 63;
  const int wv = tid >> 6;
  const int wm = (wv >> 1) * 64;
  const int wn = (wv & 1) * 64;
  const int cl = lane & 15;
  const int kh = lane >> 4;
  const long m0 = (long)blockIdx.y * 128;
  const long n0 = (long)blockIdx.x * 128;

  const int srow = tid >> 1;
  const int scolb = (tid & 1) * 32;

  f32x4 acc[4][4] = {};
  float4 pa[4];
  uint4 pb[2];

  auto issue = [&](int kt) {
    const float* ap = A + (m0 + srow) * K + kt * 32 + (tid & 1) * 16;
#pragma unroll
    for (int i = 0; i < 4; ++i) pa[i] = reinterpret_cast<const float4*>(ap)[i];
    const bf16_t* bp = Bw + (n0 + srow) * K + kt * 32 + (tid & 1) * 16;
    pb[0] = reinterpret_cast<const uint4*>(bp)[0];
    pb[1] = reinterpret_cast<const uint4*>(bp)[1];
  };
  auto commit = [&](int buf) {
    bf16x8 a0, a1;
    a0[0] = (bf16_t)pa[0].x; a0[1] = (bf16_t)pa[0].y; a0[2] = (bf16_t)pa[0].z; a0[3] = (bf16_t)pa[0].w;
    a0[4] = (bf16_t)pa[1].x; a0[5] = (bf16_t)pa[1].y; a0[6] = (bf16_t)pa[1].z; a0[7] = (bf16_t)pa[1].w;
    a1[0] = (bf16_t)pa[2].x; a1[1] = (bf16_t)pa[2].y; a1[2] = (bf16_t)pa[2].z; a1[3] = (bf16_t)pa[2].w;
    a1[4] = (bf16_t)pa[3].x; a1[5] = (bf16_t)pa[3].y; a1[6] = (bf16_t)pa[3].z; a1[7] = (bf16_t)pa[3].w;
    *reinterpret_cast<bf16x8*>(&As[buf][SWZ64(srow, scolb)]) = a0;
    *reinterpret_cast<bf16x8*>(&As[buf][SWZ64(srow, scolb + 16)]) = a1;
    *reinterpret_cast<uint4*>(&Bs[buf][SWZ64(srow, scolb)]) = pb[0];
    *reinterpret_cast<uint4*>(&Bs[buf][SWZ64(srow, scolb + 16)]) = pb[1];
  };

  issue(0);
  commit(0);
  for (int kt = 0; kt < NT; ++kt) {
    const int buf = kt & 1;
    __syncthreads();
    if (kt + 1 < NT) issue(kt + 1);
    bf16x8 af[4], bfr[4];
#pragma unroll
    for (int i = 0; i < 4; ++i)
      af[i] = *reinterpret_cast<const bf16x8*>(&As[buf][SWZ64(wm + i * 16 + cl, kh * 16)]);
#pragma unroll
    for (int j = 0; j < 4; ++j)
      bfr[j] = *reinterpret_cast<const bf16x8*>(&Bs[buf][SWZ64(wn + j * 16 + cl, kh * 16)]);
#pragma unroll
    for (int i = 0; i < 4; ++i)
#pragma unroll
      for (int j = 0; j < 4; ++j)
        acc[i][j] = MFMA_16x16x32(af[i], bfr[j], acc[i][j]);
    if (kt + 1 < NT) commit((kt + 1) & 1);
  }

  const int rl4 = kh * 4;
#pragma unroll
  for (int j = 0; j < 4; ++j) {
    const long gcol = n0 + wn + j * 16 + cl;
    const float bv = bias[gcol];
#pragma unroll
    for (int i = 0; i < 4; ++i) {
      const long grow = m0 + wm + i * 16 + rl4;
#pragma unroll
      for (int q = 0; q < 4; ++q)
        C[(grow + q) * N + gcol] = (bf16_t)(acc[i][j][q] + bv);
    }
  }
}

// ---------------- persistent scan kernel ----------------
// Round-9: clean A/B untangle of r8's regression.
//   KEEP (signature-proven in r8): U-fragments hoisted into registers
//     (bank-conflict 1.5e8 -> 1.7e7) and XCD-aligned group mapping
//     (FETCH 869 -> 574 MB).
//   REVERT (r8's regression source): all-wave dense-flag polling. Back to
//     r6's protocol verbatim: per-block flag 128B apart, storer waves store
//     h, block-wide __syncthreads (each wave drains its own vmcnt -> all h
//     acked), tid0 flags, WAVE 0 ONLY polls the group's 128 flags, sync.
//     Theory: 2048 waves hammering 2 shared MALL lines queued the producer's
//     flag store behind the read flood (MfmaUtil/VALUBusy both dropped in
//     r8 -> pure wait time).
// Geometry (r6): 256 blocks x 1024 threads, 2 groups x 128 blocks,
// 16 cols/block, waves = 2 row-tiles x 8 k-splits; vectorized float4 combine.
// Coherence (r3): h stores sc0sc1 -> MALL; h loads plain cached on virgin
// rotated slots (no fence). Fallback rot=0: ping-pong + acquire fence.
__global__ __launch_bounds__(1024, 1) void scan_k(
    const bf16_t* __restrict__ Uhi, const bf16_t* __restrict__ Ulo,
    const float* __restrict__ Ub, const bf16_t* __restrict__ XW,
    bf16_t* __restrict__ Hc, long Hstep, int rot,
    const bf16_t* __restrict__ V1w, const float* __restrict__ V1b,
    float* __restrict__ Z1,
    const float* __restrict__ V2w, const float* __restrict__ V2b,
    float* __restrict__ out, unsigned* __restrict__ slots) {
  extern __shared__ char smem[];
  char* Uh_s = smem;                        // 64 KB staging (dead after hoist)
  char* Ul_s = smem + 65536;                // 64 KB staging (dead after hoist)
  float* red = (float*)smem;                // overlay after hoist: [16][256]

  const int tid = threadIdx.x;
  const int lane = tid & 63;
  const int wv = tid >> 6;             // 0..15
  const int cl = lane & 15;
  const int kh = lane >> 4;
  const int bid = blockIdx.x;
  // XCD-aligned group split (assumes bid%8 = XCD round-robin; perf-only)
  const int g = ((bid & 7) >= 4) ? 1 : 0;
  const int j = (bid >> 3) * 4 + (bid & 3);  // group-local block id 0..127
  const int n0 = j * 16;               // owned columns
  const int r = wv >> 3;               // row-tile (0/1) within group slice
  const int ks = wv & 7;               // k-split (0..7), 256 cols each
  const int row0 = 32 * g + 16 * r;    // global batch row base for this wave
  unsigned* gslots = slots + (size_t)g * NGB * 32;  // 128B-strided per-block flags

  // ---- stage U slice into LDS (once; 1024 threads: 64 segs x 16 cols) ----
  {
    const int col = tid >> 6;          // 0..15
    const int seg = tid & 63;          // 0..63
    const char* srch = reinterpret_cast<const char*>(Uhi + (long)(n0 + col) * Hn);
    const char* srcl = reinterpret_cast<const char*>(Ulo + (long)(n0 + col) * Hn);
#pragma unroll
    for (int c = 0; c < 4; ++c) {
      const int byteoff = seg * 16 + c * 1024;
      uint4 vh = *reinterpret_cast<const uint4*>(srch + byteoff);
      uint4 vl = *reinterpret_cast<const uint4*>(srcl + byteoff);
      const int sw = col * 4096 + (byteoff ^ ((col & 7) << 4));
      *reinterpret_cast<uint4*>(Uh_s + sw) = vh;
      *reinterpret_cast<uint4*>(Ul_s + sw) = vl;
    }
  }
  __syncthreads();

  // ---- hoist this wave's 16 U fragments into registers (loop-invariant) ----
  const int lds_base = cl * 4096;
  const int lds_x = (cl & 7) << 4;
  const int kbase = ks * 512;          // byte offset of this wave's k-split
  bf16x8 Ubh0[4], Ubl0[4], Ubh1[4], Ubl1[4];  // 64 regs total
#pragma unroll
  for (int it = 0; it < 4; ++it) {
    const int kb0 = kbase + it * 128 + kh * 16;
    const int kb1 = kb0 + 64;
    Ubh0[it] = *reinterpret_cast<const bf16x8*>(Uh_s + lds_base + (kb0 ^ lds_x));
    Ubl0[it] = *reinterpret_cast<const bf16x8*>(Ul_s + lds_base + (kb0 ^ lds_x));
    Ubh1[it] = *reinterpret_cast<const bf16x8*>(Uh_s + lds_base + (kb1 ^ lds_x));
    Ubl1[it] = *reinterpret_cast<const bf16x8*>(Ul_s + lds_base + (kb1 ^ lds_x));
  }
  __syncthreads();  // all waves hoisted; LDS reusable as red

  // store-side mapping (storer waves ks==0): one coalesced u64 per lane
  const int st_row = lane >> 2;        // 0..15
  const int st_cg = lane & 3;          // col group *4
  const bool storer = (ks == 0);

  float4 bv4 = {0.f, 0.f, 0.f, 0.f};
  if (storer) bv4 = *reinterpret_cast<const float4*>(Ub + n0 + st_cg * 4);
  const long xw_off = (long)(row0 + st_row) * (Tn * Hn) + n0 + st_cg * 4;

  // prefetch xw add-path for t=0 (storer waves)
  bf16x4 ad = {};
  if (storer) ad = *reinterpret_cast<const bf16x4*>(XW + xw_off);

  // h slot pointers: t reads hin, writes hout.
  bf16_t* hin = Hc;            // slot 0 = zeros
  bf16_t* hout = Hc + Hstep;   // slot 1

  for (int t = 0; t < Tn; ++t) {
    const bf16_t* arow = hin + (long)(row0 + cl) * Hn + ks * 256 + kh * 8;

    f32x4 ah0 = {}, ah1 = {}, al0 = {}, al1 = {};
#pragma unroll
    for (int it = 0; it < 4; ++it) {
      bf16x8 a0 = *reinterpret_cast<const bf16x8*>(arow + it * 64);
      bf16x8 a1 = *reinterpret_cast<const bf16x8*>(arow + it * 64 + 32);
      ah0 = MFMA_16x16x32(a0, Ubh0[it], ah0);
      al0 = MFMA_16x16x32(a0, Ubl0[it], al0);
      ah1 = MFMA_16x16x32(a1, Ubh1[it], ah1);
      al1 = MFMA_16x16x32(a1, Ubl1[it], al1);
    }

    __syncthreads();  // A: step t-1's combine finished reading red

    // k-split partials -> LDS
#pragma unroll
    for (int q = 0; q < 4; ++q)
      red[wv * 256 + (kh * 4 + q) * 16 + cl] = ah0[q] + ah1[q] + al0[q] + al1[q];

    __syncthreads();  // B: all partials visible

    // storer waves: combine 8 k-splits (float4, conflict-free), bias+xw+relu,
    // one coalesced sc0sc1 store
    if (storer) {
      const int ri = st_row * 16 + st_cg * 4;
      float4 s = {0.f, 0.f, 0.f, 0.f};
#pragma unroll
      for (int w = 0; w < 8; ++w) {
        float4 p = *reinterpret_cast<const float4*>(&red[(wv + w) * 256 + ri]);
        s.x += p.x; s.y += p.y; s.z += p.z; s.w += p.w;
      }
      bf16x4 hv;
      hv[0] = (bf16_t)fmaxf(s.x + bv4.x + (float)ad[0], 0.f);
      hv[1] = (bf16_t)fmaxf(s.y + bv4.y + (float)ad[1], 0.f);
      hv[2] = (bf16_t)fmaxf(s.z + bv4.z + (float)ad[2], 0.f);
      hv[3] = (bf16_t)fmaxf(s.w + bv4.w + (float)ad[3], 0.f);
      __hip_atomic_store(
          reinterpret_cast<u64*>(hout + (long)(row0 + st_row) * Hn + n0 + st_cg * 4),
          *reinterpret_cast<const u64*>(&hv), __ATOMIC_RELAXED,
          __HIP_MEMORY_SCOPE_AGENT);
    }

    // ---- group-local broadcast barrier (r6 protocol) ----
    const unsigned tgt = (unsigned)(t + 1);
    __syncthreads();  // each wave drains its own vmcnt: all h-stores acked
    asm volatile("" ::: "memory");
    if (tid == 0)
      __hip_atomic_store(gslots + (size_t)j * 32, tgt,
                         __ATOMIC_RELAXED, __HIP_MEMORY_SCOPE_AGENT);

    // prefetch XW for t+1 — hides under the poll
    bf16x4 adn = {};
    if (storer && (t + 1 < Tn))
      adn = *reinterpret_cast<const bf16x4*>(XW + xw_off + (long)(t + 1) * Hn);

    if (tid < 64) {  // wave 0 ONLY polls this group's 128 flags
      for (;;) {
        unsigned a = __hip_atomic_load(gslots + (size_t)tid * 32,
                                       __ATOMIC_RELAXED, __HIP_MEMORY_SCOPE_AGENT);
        unsigned b = __hip_atomic_load(gslots + (size_t)(tid + 64) * 32,
                                       __ATOMIC_RELAXED, __HIP_MEMORY_SCOPE_AGENT);
        if (__all((a >= tgt) && (b >= tgt))) break;
      }
      // rotation: no fence needed (virgin addresses can't be stale).
      if (!rot) __builtin_amdgcn_fence(__ATOMIC_ACQUIRE, "agent");
    }
    asm volatile("" ::: "memory");
    __syncthreads();

    ad = adn;

    // advance slots
    bf16_t* nn = hout;
    hout = rot ? (hout + Hstep) : hin;
    hin = nn;
  }

  // ---- V1 layer: z1 = relu(h_last @ V1^T + b1) for this group's 32 rows ----
  {
    const bf16_t* arow = hin + (long)(row0 + cl) * Hn + ks * 256 + kh * 8;
    const bf16_t* vrow = V1w + (long)(n0 + cl) * Hn + ks * 256 + kh * 8;
    f32x4 z0 = {}, z1a = {};
#pragma unroll
    for (int it = 0; it < 4; ++it) {
      bf16x8 a0 = *reinterpret_cast<const bf16x8*>(arow + it * 64);
      bf16x8 a1 = *reinterpret_cast<const bf16x8*>(arow + it * 64 + 32);
      bf16x8 b0 = *reinterpret_cast<const bf16x8*>(vrow + it * 64);
      bf16x8 b1 = *reinterpret_cast<const bf16x8*>(vrow + it * 64 + 32);
      z0 = MFMA_16x16x32(a0, b0, z0);
      z1a = MFMA_16x16x32(a1, b1, z1a);
    }
#pragma unroll
    for (int q = 0; q < 4; ++q)
      red[wv * 256 + (kh * 4 + q) * 16 + cl] = z0[q] + z1a[q];
    __syncthreads();
    if (storer) {
      const int ri = st_row * 16 + st_cg * 4;
      float4 s = {0.f, 0.f, 0.f, 0.f};
#pragma unroll
      for (int w = 0; w < 8; ++w) {
        float4 p = *reinterpret_cast<const float4*>(&red[(wv + w) * 256 + ri]);
        s.x += p.x; s.y += p.y; s.z += p.z; s.w += p.w;
      }
      float4 vb = *reinterpret_cast<const float4*>(V1b + n0 + st_cg * 4);
      float4 o;
      o.x = fmaxf(s.x + vb.x, 0.f);
      o.y = fmaxf(s.y + vb.y, 0.f);
      o.z = fmaxf(s.z + vb.z, 0.f);
      o.w = fmaxf(s.w + vb.w, 0.f);
      *reinterpret_cast<float4*>(Z1 + (long)(row0 + st_row) * Hn + n0 + st_cg * 4) = o;
    }
  }

  // ---- FULL-grid barrier before head reads Z1 (release + acquire, once) ----
  {
    unsigned* fbar = slots + (size_t)NBT * 32;  // after group flags
    __syncthreads();
    if (tid == 0)
      __hip_atomic_store(fbar + (size_t)bid * 32, 1u,
                         __ATOMIC_RELEASE, __HIP_MEMORY_SCOPE_AGENT);
    if (tid < 64) {
      for (;;) {
        unsigned a = __hip_atomic_load(fbar + (size_t)tid * 32,
                                       __ATOMIC_RELAXED, __HIP_MEMORY_SCOPE_AGENT);
        unsigned b = __hip_atomic_load(fbar + (size_t)(tid + 64) * 32,
                                       __ATOMIC_RELAXED, __HIP_MEMORY_SCOPE_AGENT);
        unsigned c = __hip_atomic_load(fbar + (size_t)(tid + 128) * 32,
                                       __ATOMIC_RELAXED, __HIP_MEMORY_SCOPE_AGENT);
        unsigned d = __hip_atomic_load(fbar + (size_t)(tid + 192) * 32,
                                       __ATOMIC_RELAXED, __HIP_MEMORY_SCOPE_AGENT);
        if (__all((int)((a >= 1u) && (b >= 1u) && (c >= 1u) && (d >= 1u)))) break;
      }
      __builtin_amdgcn_fence(__ATOMIC_ACQUIRE, "agent");
    }
    __syncthreads();
  }

  // ---- head: z2 = relu(z1 @ V2^T + b2); out = log_softmax ----
  if (bid < Bn) {
    const int b = bid;
    float p[Cn] = {0.f, 0.f, 0.f, 0.f, 0.f};
    for (int jj = tid; jj < Hn; jj += 1024) {
      const float x = Z1[(long)b * Hn + jj];
#pragma unroll
      for (int c = 0; c < Cn; ++c) p[c] += x * V2w[(long)c * Hn + jj];
    }
#pragma unroll
    for (int c = 0; c < Cn; ++c)
      for (int off = 32; off; off >>= 1) p[c] += __shfl_down(p[c], off, 64);

    float* redh = reinterpret_cast<float*>(smem);
    if (lane == 0) {
#pragma unroll
      for (int c = 0; c < Cn; ++c) redh[c * NW + wv] = p[c];
    }
    __syncthreads();
    if (tid == 0) {
      float z[Cn];
      float mx = 0.f;
#pragma unroll
      for (int c = 0; c < Cn; ++c) {
        float s16 = 0.f;
#pragma unroll
        for (int w = 0; w < NW; ++w) s16 += redh[c * NW + w];
        z[c] = fmaxf(s16 + V2b[c], 0.f);
        mx = fmaxf(mx, z[c]);
      }
      float s = 0.f;
#pragma unroll
      for (int c = 0; c < Cn; ++c) s += expf(z[c] - mx);
      const float ls = logf(s);
#pragma unroll
      for (int c = 0; c < Cn; ++c) out[b * Cn + c] = z[c] - mx - ls;
    }
  }
}

// ---------------- host ----------------
extern "C" void kernel_launch(void* const* d_in, const int* in_sizes, int n_in,
                              void* d_out, int out_size, void* d_ws, size_t ws_size,
                              hipStream_t stream) {
  const float* inputs = (const float*)d_in[0];
  const float* W_w = (const float*)d_in[1];
  const float* W_b = (const float*)d_in[2];
  const float* U_w = (const float*)d_in[3];
  const float* U_b = (const float*)d_in[4];
  const float* V1_w = (const float*)d_in[5];
  const float* V1_b = (const float*)d_in[6];
  const float* V2_w = (const float*)d_in[7];
  const float* V2_b = (const float*)d_in[8];
  float* out = (float*)d_out;

  size_t off = 0;
  auto alloc = [&](size_t bytes) {
    void* p = (char*)d_ws + off;
    off += (bytes + 255) & ~(size_t)255;
    return p;
  };
  bf16_t* Wbf = (bf16_t*)alloc((size_t)Hn * Dn * 2);
  bf16_t* Uhi = (bf16_t*)alloc((size_t)Hn * Hn * 2);
  bf16_t* Ulo = (bf16_t*)alloc((size_t)Hn * Hn * 2);
  bf16_t* V1bf = (bf16_t*)alloc((size_t)Hn * Hn * 2);
  bf16_t* XW = (bf16_t*)alloc((size_t)Bn * Tn * Hn * 2);
  float* Z1 = (float*)alloc((size_t)Bn * Hn * 4);
  // group flags (NBT slots, 128B each) + full-barrier slots (NBT, 128B each)
  const size_t slots_bytes = (size_t)(NBT * 32 * 2) * 4;  // 64 KB
  unsigned* slots = (unsigned*)alloc(slots_bytes);

  // h chain: rotation if the workspace fits Tn+1 virgin slots, else ping-pong.
  const size_t slot_bytes = (size_t)Bn * Hn * 2;  // 256 KB
  const size_t rot_bytes = (size_t)(Tn + 1) * slot_bytes;
  const int rot = (ws_size - off) >= (rot_bytes + 256) ? 1 : 0;
  bf16_t* Hc = (bf16_t*)alloc(rot ? rot_bytes : 2 * slot_bytes);
  (void)ws_size;

  (void)hipFuncSetAttribute((const void*)scan_k,
                            hipFuncAttributeMaxDynamicSharedMemorySize, 131072);

  cvt_bf16_k<<<(Hn * Dn / 4 + 255) / 256, 256, 0, stream>>>(W_w, Wbf, Hn * Dn / 4);
  cvt_hilo_k<<<(Hn * Hn / 4 + 255) / 256, 256, 0, stream>>>(U_w, Uhi, Ulo, Hn * Hn / 4);
  cvt_bf16_k<<<(Hn * Hn / 4 + 255) / 256, 256, 0, stream>>>(V1_w, V1bf, Hn * Hn / 4);

  gemm_xw_k<<<dim3(Hn / 128, (Bn * Tn) / 128), 256, 0, stream>>>(inputs, Wbf, W_b, XW);

  (void)hipMemsetAsync(Hc, 0, slot_bytes, stream);  // slot 0 = h_0 = zeros
  (void)hipMemsetAsync(slots, 0, slots_bytes, stream);

  scan_k<<<NBT, 1024, 131072, stream>>>(Uhi, Ulo, U_b, XW, Hc, (long)Bn * Hn, rot,
                                        V1bf, V1_b, Z1, V2_w, V2_b, out, slots);
}

// Round 10
// 2600.437 us; speedup vs baseline: 1.8752x; 1.2487x over previous
//
#include <hip/hip_runtime.h>
#include <math.h>

typedef __bf16 bf16_t;
typedef __bf16 bf16x4 __attribute__((ext_vector_type(4)));
typedef __bf16 bf16x8 __attribute__((ext_vector_type(8)));
typedef float f32x4 __attribute__((ext_vector_type(4)));
typedef unsigned long long u64;

#define MFMA_16x16x32(A, B, C) __builtin_amdgcn_mfma_f32_16x16x32_bf16((A), (B), (C), 0, 0, 0)

static constexpr int Bn = 64;    // batch
static constexpr int Tn = 512;   // time
static constexpr int Dn = 1024;  // input dim
static constexpr int Hn = 2048;  // hidden
static constexpr int Cn = 5;     // classes
static constexpr int NGB = 64;   // blocks per batch-group
static constexpr int NGRP = 4;   // batch groups (16 rows each)
static constexpr int NBT = NGB * NGRP;  // 256 blocks = full GPU
static constexpr int NW = 16;    // waves per block (1024 threads)

// LDS swizzle for the xw GEMM tiles (32 bf16 = 64B rows)
#define SWZ64(row, kb)  ((((row) * 64) + (kb)) ^ (((row) & 3) << 4))

// ---------------- conversion kernels ----------------
__global__ __launch_bounds__(256) void cvt_bf16_k(const float* __restrict__ in,
                                                  bf16_t* __restrict__ out, int n4) {
  int i = blockIdx.x * 256 + threadIdx.x;
  if (i >= n4) return;
  float4 v = reinterpret_cast<const float4*>(in)[i];
  bf16x4 o;
  o[0] = (bf16_t)v.x; o[1] = (bf16_t)v.y; o[2] = (bf16_t)v.z; o[3] = (bf16_t)v.w;
  reinterpret_cast<bf16x4*>(out)[i] = o;
}

__global__ __launch_bounds__(256) void cvt_hilo_k(const float* __restrict__ in,
                                                  bf16_t* __restrict__ hi,
                                                  bf16_t* __restrict__ lo, int n4) {
  int i = blockIdx.x * 256 + threadIdx.x;
  if (i >= n4) return;
  float4 v = reinterpret_cast<const float4*>(in)[i];
  float f[4] = {v.x, v.y, v.z, v.w};
  bf16x4 h, l;
#pragma unroll
  for (int j = 0; j < 4; ++j) {
    bf16_t hb = (bf16_t)f[j];
    h[j] = hb;
    l[j] = (bf16_t)(f[j] - (float)hb);
  }
  reinterpret_cast<bf16x4*>(hi)[i] = h;
  reinterpret_cast<bf16x4*>(lo)[i] = l;
}

// ---------------- xw projection GEMM ----------------
__global__ __launch_bounds__(256) void gemm_xw_k(const float* __restrict__ A,
                                                 const bf16_t* __restrict__ Bw,
                                                 const float* __restrict__ bias,
                                                 bf16_t* __restrict__ C) {
  constexpr int K = Dn;
  constexpr int N = Hn;
  constexpr int NT = K / 32;
  __shared__ char As[2][128 * 64];
  __shared__ char Bs[2][128 * 64];

  const int tid = threadIdx.x;
  const int lane = tid & 63;
  const int wv = tid >> 6;
  const int wm = (wv >> 1) * 64;
  const int wn = (wv & 1) * 64;
  const int cl = lane & 15;
  const int kh = lane >> 4;
  const long m0 = (long)blockIdx.y * 128;
  const long n0 = (long)blockIdx.x * 128;

  const int srow = tid >> 1;
  const int scolb = (tid & 1) * 32;

  f32x4 acc[4][4] = {};
  float4 pa[4];
  uint4 pb[2];

  auto issue = [&](int kt) {
    const float* ap = A + (m0 + srow) * K + kt * 32 + (tid & 1) * 16;
#pragma unroll
    for (int i = 0; i < 4; ++i) pa[i] = reinterpret_cast<const float4*>(ap)[i];
    const bf16_t* bp = Bw + (n0 + srow) * K + kt * 32 + (tid & 1) * 16;
    pb[0] = reinterpret_cast<const uint4*>(bp)[0];
    pb[1] = reinterpret_cast<const uint4*>(bp)[1];
  };
  auto commit = [&](int buf) {
    bf16x8 a0, a1;
    a0[0] = (bf16_t)pa[0].x; a0[1] = (bf16_t)pa[0].y; a0[2] = (bf16_t)pa[0].z; a0[3] = (bf16_t)pa[0].w;
    a0[4] = (bf16_t)pa[1].x; a0[5] = (bf16_t)pa[1].y; a0[6] = (bf16_t)pa[1].z; a0[7] = (bf16_t)pa[1].w;
    a1[0] = (bf16_t)pa[2].x; a1[1] = (bf16_t)pa[2].y; a1[2] = (bf16_t)pa[2].z; a1[3] = (bf16_t)pa[2].w;
    a1[4] = (bf16_t)pa[3].x; a1[5] = (bf16_t)pa[3].y; a1[6] = (bf16_t)pa[3].z; a1[7] = (bf16_t)pa[3].w;
    *reinterpret_cast<bf16x8*>(&As[buf][SWZ64(srow, scolb)]) = a0;
    *reinterpret_cast<bf16x8*>(&As[buf][SWZ64(srow, scolb + 16)]) = a1;
    *reinterpret_cast<uint4*>(&Bs[buf][SWZ64(srow, scolb)]) = pb[0];
    *reinterpret_cast<uint4*>(&Bs[buf][SWZ64(srow, scolb + 16)]) = pb[1];
  };

  issue(0);
  commit(0);
  for (int kt = 0; kt < NT; ++kt) {
    const int buf = kt & 1;
    __syncthreads();
    if (kt + 1 < NT) issue(kt + 1);
    bf16x8 af[4], bfr[4];
#pragma unroll
    for (int i = 0; i < 4; ++i)
      af[i] = *reinterpret_cast<const bf16x8*>(&As[buf][SWZ64(wm + i * 16 + cl, kh * 16)]);
#pragma unroll
    for (int j = 0; j < 4; ++j)
      bfr[j] = *reinterpret_cast<const bf16x8*>(&Bs[buf][SWZ64(wn + j * 16 + cl, kh * 16)]);
#pragma unroll
    for (int i = 0; i < 4; ++i)
#pragma unroll
      for (int j = 0; j < 4; ++j)
        acc[i][j] = MFMA_16x16x32(af[i], bfr[j], acc[i][j]);
    if (kt + 1 < NT) commit((kt + 1) & 1);
  }

  const int rl4 = kh * 4;
#pragma unroll
  for (int j = 0; j < 4; ++j) {
    const long gcol = n0 + wn + j * 16 + cl;
    const float bv = bias[gcol];
#pragma unroll
    for (int i = 0; i < 4; ++i) {
      const long grow = m0 + wm + i * 16 + rl4;
#pragma unroll
      for (int q = 0; q < 4; ++q)
        C[(grow + q) * N + gcol] = (bf16_t)(acc[i][j][q] + bv);
    }
  }
}

// ---------------- persistent scan kernel ----------------
// Round-10: RESHAPED TILES. 256 blocks x 1024 threads (16 waves).
//   4 groups x 16 batch rows; 64 blocks/group each owning 32 cols.
//   Waves = 16 k-splits of 128 K each (no row-tiling: the group's 16 rows
//   fit one MFMA M). Per block h read = 16x2048x2B = 64 KB/step (HALF of
//   r9) -> per-XCD L2 traffic 4 -> 2 MB/step. Barrier population 64 blocks.
//   Groups map to XCD pairs: g=(bid&7)>>1 (perf heuristic only).
//   U fragments (2 ct x 4 ksub, hi+lo = 64 VGPRs) loaded DIRECTLY from
//   global once -> no LDS staging; LDS = double-buffered red only.
//   2 syncs/step: red parity removes the pre-MFMA sync; TWO storer waves
//   (8 rows each) store h, drain wave-locally (r7-proven), flag; wave 0
//   polls the group's 128 flags (2 loads/lane), sync releases.
// Coherence (r3): h stores sc0sc1 -> MALL; h loads plain cached on virgin
// rotated slots (no fence). Fallback rot=0: ping-pong + acquire fence.
__global__ __launch_bounds__(1024, 1) void scan_k(
    const bf16_t* __restrict__ Uhi, const bf16_t* __restrict__ Ulo,
    const float* __restrict__ Ub, const bf16_t* __restrict__ XW,
    bf16_t* __restrict__ Hc, long Hstep, int rot,
    const bf16_t* __restrict__ V1w, const float* __restrict__ V1b,
    float* __restrict__ Z1,
    const float* __restrict__ V2w, const float* __restrict__ V2b,
    float* __restrict__ out, unsigned* __restrict__ slots) {
  extern __shared__ char smem[];
  float* redb = (float*)smem;  // red[2][16][512] f32 = 64 KB

  const int tid = threadIdx.x;
  const int lane = tid & 63;
  const int wv = tid >> 6;             // 0..15 = k-split (128 K each)
  const int cl = lane & 15;
  const int kh = lane >> 4;
  const int bid = blockIdx.x;
  // XCD-pair group mapping (assumes bid%8 = XCD round-robin; perf-only)
  const int g = (bid & 7) >> 1;              // group 0..3
  const int j = (bid >> 3) * 2 + (bid & 1);  // group-local block 0..63
  const int n0 = j * 32;               // owned 32 columns
  const int row0 = g * 16;             // group's 16 batch rows
  unsigned* gflags = slots + (size_t)g * (NGB * 2 * 32);  // 128 slots, 128B apart

  // ---- U fragments direct from global (one-time; loop-invariant) ----
  bf16x8 Ubh[2][4], Ubl[2][4];  // [col-tile][ksub] = 64 VGPRs
#pragma unroll
  for (int ct = 0; ct < 2; ++ct)
#pragma unroll
    for (int ksub = 0; ksub < 4; ++ksub) {
      const long uoff = (long)(n0 + ct * 16 + cl) * Hn + wv * 128 + ksub * 32 + kh * 8;
      Ubh[ct][ksub] = *reinterpret_cast<const bf16x8*>(Uhi + uoff);
      Ubl[ct][ksub] = *reinterpret_cast<const bf16x8*>(Ulo + uoff);
    }

  // storer waves: wv 0,1 each own 8 rows x 32 cols (4 outputs/lane)
  const bool storer = (wv < 2);
  const int srow = (wv & 1) * 8 + (lane >> 3);   // 0..15
  const int scol = (lane & 7) * 4;               // col group of 4
  float4 bv4 = {0.f, 0.f, 0.f, 0.f};
  if (storer) bv4 = *reinterpret_cast<const float4*>(Ub + n0 + scol);
  const long xw_off = (long)(row0 + srow) * (Tn * Hn) + n0 + scol;

  bf16x4 ad = {};
  if (storer) ad = *reinterpret_cast<const bf16x4*>(XW + xw_off);

  bf16_t* hin = Hc;            // slot 0 = zeros
  bf16_t* hout = Hc + Hstep;   // slot 1

  for (int t = 0; t < Tn; ++t) {
    const bf16_t* arow = hin + (long)(row0 + cl) * Hn + wv * 128 + kh * 8;

    bf16x8 a[4];
#pragma unroll
    for (int ksub = 0; ksub < 4; ++ksub)
      a[ksub] = *reinterpret_cast<const bf16x8*>(arow + ksub * 32);

    f32x4 acch[2] = {}, accl[2] = {};
#pragma unroll
    for (int ksub = 0; ksub < 4; ++ksub) {
      acch[0] = MFMA_16x16x32(a[ksub], Ubh[0][ksub], acch[0]);
      accl[0] = MFMA_16x16x32(a[ksub], Ubl[0][ksub], accl[0]);
      acch[1] = MFMA_16x16x32(a[ksub], Ubh[1][ksub], acch[1]);
      accl[1] = MFMA_16x16x32(a[ksub], Ubl[1][ksub], accl[1]);
    }

    // k-split partials -> red[t&1] (double-buffered: no pre-sync needed)
    float* red = redb + (t & 1) * 8192;
#pragma unroll
    for (int ct = 0; ct < 2; ++ct)
#pragma unroll
      for (int q = 0; q < 4; ++q)
        red[wv * 512 + (kh * 4 + q) * 32 + ct * 16 + cl] = acch[ct][q] + accl[ct][q];

    __syncthreads();  // sync B: all partials visible

    // storer waves: combine 16 k-splits (contiguous 1KB float4 reads),
    // bias+xw+relu, one u64 sc0sc1 store, WAVE-LOCAL drain, flag.
    if (storer) {
      const int ri = srow * 32 + scol;
      float4 s = {0.f, 0.f, 0.f, 0.f};
#pragma unroll
      for (int w = 0; w < NW; ++w) {
        float4 p = *reinterpret_cast<const float4*>(&red[w * 512 + ri]);
        s.x += p.x; s.y += p.y; s.z += p.z; s.w += p.w;
      }
      bf16x4 hv;
      hv[0] = (bf16_t)fmaxf(s.x + bv4.x + (float)ad[0], 0.f);
      hv[1] = (bf16_t)fmaxf(s.y + bv4.y + (float)ad[1], 0.f);
      hv[2] = (bf16_t)fmaxf(s.z + bv4.z + (float)ad[2], 0.f);
      hv[3] = (bf16_t)fmaxf(s.w + bv4.w + (float)ad[3], 0.f);
      __hip_atomic_store(
          reinterpret_cast<u64*>(hout + (long)(row0 + srow) * Hn + n0 + scol),
          *reinterpret_cast<const u64*>(&hv), __ATOMIC_RELAXED,
          __HIP_MEMORY_SCOPE_AGENT);
      asm volatile("s_waitcnt vmcnt(0)" ::: "memory");  // own h acked at MALL
      if (lane == 0)
        __hip_atomic_store(gflags + (size_t)(j * 2 + wv) * 32, (unsigned)(t + 1),
                           __ATOMIC_RELAXED, __HIP_MEMORY_SCOPE_AGENT);
      if (t + 1 < Tn)  // xw prefetch hides under poll/sync
        ad = *reinterpret_cast<const bf16x4*>(XW + xw_off + (long)(t + 1) * Hn);
    }

    const unsigned tgt = (unsigned)(t + 1);
    if (wv == 0) {  // wave 0 polls the group's 128 flags (2 loads/lane)
      for (;;) {
        unsigned a0 = __hip_atomic_load(gflags + (size_t)lane * 32,
                                        __ATOMIC_RELAXED, __HIP_MEMORY_SCOPE_AGENT);
        unsigned b0 = __hip_atomic_load(gflags + (size_t)(lane + 64) * 32,
                                        __ATOMIC_RELAXED, __HIP_MEMORY_SCOPE_AGENT);
        if (__all((a0 >= tgt) && (b0 >= tgt))) break;
      }
      // rotation: no fence needed (virgin addresses can't be stale).
      if (!rot) __builtin_amdgcn_fence(__ATOMIC_ACQUIRE, "agent");
    }
    asm volatile("" ::: "memory");
    __syncthreads();  // sync D: release

    // advance slots
    bf16_t* nn = hout;
    hout = rot ? (hout + Hstep) : hin;
    hin = nn;
  }

  // ---- V1 layer: z1 = relu(h_last @ V1^T + b1) for this group's 16 rows ----
  {
    const bf16_t* arow = hin + (long)(row0 + cl) * Hn + wv * 128 + kh * 8;
    f32x4 z[2] = {};
#pragma unroll
    for (int ksub = 0; ksub < 4; ++ksub) {
      bf16x8 a0 = *reinterpret_cast<const bf16x8*>(arow + ksub * 32);
#pragma unroll
      for (int ct = 0; ct < 2; ++ct) {
        const long voff = (long)(n0 + ct * 16 + cl) * Hn + wv * 128 + ksub * 32 + kh * 8;
        bf16x8 b0 = *reinterpret_cast<const bf16x8*>(V1w + voff);
        z[ct] = MFMA_16x16x32(a0, b0, z[ct]);
      }
    }
    float* red = redb;  // buffer 0: last reader finished before final sync D
#pragma unroll
    for (int ct = 0; ct < 2; ++ct)
#pragma unroll
      for (int q = 0; q < 4; ++q)
        red[wv * 512 + (kh * 4 + q) * 32 + ct * 16 + cl] = z[ct][q];
    __syncthreads();
    if (storer) {
      const int ri = srow * 32 + scol;
      float4 s = {0.f, 0.f, 0.f, 0.f};
#pragma unroll
      for (int w = 0; w < NW; ++w) {
        float4 p = *reinterpret_cast<const float4*>(&red[w * 512 + ri]);
        s.x += p.x; s.y += p.y; s.z += p.z; s.w += p.w;
      }
      float4 vb = *reinterpret_cast<const float4*>(V1b + n0 + scol);
      float4 o;
      o.x = fmaxf(s.x + vb.x, 0.f);
      o.y = fmaxf(s.y + vb.y, 0.f);
      o.z = fmaxf(s.z + vb.z, 0.f);
      o.w = fmaxf(s.w + vb.w, 0.f);
      *reinterpret_cast<float4*>(Z1 + (long)(row0 + srow) * Hn + n0 + scol) = o;
    }
  }

  // ---- FULL-grid barrier before head reads Z1 (release + acquire, once) ----
  {
    unsigned* fbar = slots + (size_t)NGRP * NGB * 2 * 32;  // after group flags
    __syncthreads();
    if (tid == 0)
      __hip_atomic_store(fbar + (size_t)bid * 32, 1u,
                         __ATOMIC_RELEASE, __HIP_MEMORY_SCOPE_AGENT);
    if (tid < 64) {
      for (;;) {
        unsigned a = __hip_atomic_load(fbar + (size_t)tid * 32,
                                       __ATOMIC_RELAXED, __HIP_MEMORY_SCOPE_AGENT);
        unsigned b = __hip_atomic_load(fbar + (size_t)(tid + 64) * 32,
                                       __ATOMIC_RELAXED, __HIP_MEMORY_SCOPE_AGENT);
        unsigned c = __hip_atomic_load(fbar + (size_t)(tid + 128) * 32,
                                       __ATOMIC_RELAXED, __HIP_MEMORY_SCOPE_AGENT);
        unsigned d = __hip_atomic_load(fbar + (size_t)(tid + 192) * 32,
                                       __ATOMIC_RELAXED, __HIP_MEMORY_SCOPE_AGENT);
        if (__all((int)((a >= 1u) && (b >= 1u) && (c >= 1u) && (d >= 1u)))) break;
      }
      __builtin_amdgcn_fence(__ATOMIC_ACQUIRE, "agent");
    }
    __syncthreads();
  }

  // ---- head: z2 = relu(z1 @ V2^T + b2); out = log_softmax ----
  if (bid < Bn) {
    const int b = bid;
    float p[Cn] = {0.f, 0.f, 0.f, 0.f, 0.f};
    for (int jj = tid; jj < Hn; jj += 1024) {
      const float x = Z1[(long)b * Hn + jj];
#pragma unroll
      for (int c = 0; c < Cn; ++c) p[c] += x * V2w[(long)c * Hn + jj];
    }
#pragma unroll
    for (int c = 0; c < Cn; ++c)
      for (int off = 32; off; off >>= 1) p[c] += __shfl_down(p[c], off, 64);

    float* redh = reinterpret_cast<float*>(smem);
    if (lane == 0) {
#pragma unroll
      for (int c = 0; c < Cn; ++c) redh[c * NW + wv] = p[c];
    }
    __syncthreads();
    if (tid == 0) {
      float z[Cn];
      float mx = 0.f;
#pragma unroll
      for (int c = 0; c < Cn; ++c) {
        float s16 = 0.f;
#pragma unroll
        for (int w = 0; w < NW; ++w) s16 += redh[c * NW + w];
        z[c] = fmaxf(s16 + V2b[c], 0.f);
        mx = fmaxf(mx, z[c]);
      }
      float s = 0.f;
#pragma unroll
      for (int c = 0; c < Cn; ++c) s += expf(z[c] - mx);
      const float ls = logf(s);
#pragma unroll
      for (int c = 0; c < Cn; ++c) out[b * Cn + c] = z[c] - mx - ls;
    }
  }
}

// ---------------- host ----------------
extern "C" void kernel_launch(void* const* d_in, const int* in_sizes, int n_in,
                              void* d_out, int out_size, void* d_ws, size_t ws_size,
                              hipStream_t stream) {
  const float* inputs = (const float*)d_in[0];
  const float* W_w = (const float*)d_in[1];
  const float* W_b = (const float*)d_in[2];
  const float* U_w = (const float*)d_in[3];
  const float* U_b = (const float*)d_in[4];
  const float* V1_w = (const float*)d_in[5];
  const float* V1_b = (const float*)d_in[6];
  const float* V2_w = (const float*)d_in[7];
  const float* V2_b = (const float*)d_in[8];
  float* out = (float*)d_out;

  size_t off = 0;
  auto alloc = [&](size_t bytes) {
    void* p = (char*)d_ws + off;
    off += (bytes + 255) & ~(size_t)255;
    return p;
  };
  bf16_t* Wbf = (bf16_t*)alloc((size_t)Hn * Dn * 2);
  bf16_t* Uhi = (bf16_t*)alloc((size_t)Hn * Hn * 2);
  bf16_t* Ulo = (bf16_t*)alloc((size_t)Hn * Hn * 2);
  bf16_t* V1bf = (bf16_t*)alloc((size_t)Hn * Hn * 2);
  bf16_t* XW = (bf16_t*)alloc((size_t)Bn * Tn * Hn * 2);
  float* Z1 = (float*)alloc((size_t)Bn * Hn * 4);
  // group flags (NGRP*NGB*2 slots, 128B each) + full-barrier (NBT, 128B each)
  const size_t slots_bytes = (size_t)(NGRP * NGB * 2 * 32 + NBT * 32) * 4;  // 96 KB
  unsigned* slots = (unsigned*)alloc(slots_bytes);

  // h chain: rotation if the workspace fits Tn+1 virgin slots, else ping-pong.
  const size_t slot_bytes = (size_t)Bn * Hn * 2;  // 256 KB
  const size_t rot_bytes = (size_t)(Tn + 1) * slot_bytes;
  const int rot = (ws_size - off) >= (rot_bytes + 256) ? 1 : 0;
  bf16_t* Hc = (bf16_t*)alloc(rot ? rot_bytes : 2 * slot_bytes);
  (void)ws_size;

  (void)hipFuncSetAttribute((const void*)scan_k,
                            hipFuncAttributeMaxDynamicSharedMemorySize, 65536);

  cvt_bf16_k<<<(Hn * Dn / 4 + 255) / 256, 256, 0, stream>>>(W_w, Wbf, Hn * Dn / 4);
  cvt_hilo_k<<<(Hn * Hn / 4 + 255) / 256, 256, 0, stream>>>(U_w, Uhi, Ulo, Hn * Hn / 4);
  cvt_bf16_k<<<(Hn * Hn / 4 + 255) / 256, 256, 0, stream>>>(V1_w, V1bf, Hn * Hn / 4);

  gemm_xw_k<<<dim3(Hn / 128, (Bn * Tn) / 128), 256, 0, stream>>>(inputs, Wbf, W_b, XW);

  (void)hipMemsetAsync(Hc, 0, slot_bytes, stream);  // slot 0 = h_0 = zeros
  (void)hipMemsetAsync(slots, 0, slots_bytes, stream);

  scan_k<<<NBT, 1024, 65536, stream>>>(Uhi, Ulo, U_b, XW, Hc, (long)Bn * Hn, rot,
                                       V1bf, V1_b, Z1, V2_w, V2_b, out, slots);
}